// Round 4
// baseline (25633.868 us; speedup 1.0000x reference)
//
#include <hip/hip_runtime.h>

typedef __attribute__((ext_vector_type(4))) float f32x4;
typedef __attribute__((ext_vector_type(8))) short bf16x8;

#define DEV __device__ __forceinline__

DEV float b2f(ushort u) { return __uint_as_float(((uint)u) << 16); }
DEV ushort f2b(float f) {
    uint u = __float_as_uint(f);
    return (ushort)((u + 0x7fffu + ((u >> 16) & 1u)) >> 16);  // RNE
}
DEV float fsig(float x) {
    x = fminf(fmaxf(x, -30.f), 30.f);
    return 1.f / (1.f + __expf(-x));
}
DEV float ftanh(float x) {
    x = fminf(fmaxf(x, -15.f), 15.f);
    float e = __expf(2.f * x);
    return (e - 1.f) / (e + 1.f);
}
DEV void gload_lds16(const void* g, void* l) {
    __builtin_amdgcn_global_load_lds(
        (const __attribute__((address_space(1))) void*)g,
        (__attribute__((address_space(3))) void*)l, 16, 0, 0);
}

// ---------------- f32 -> bf16 weight conversion ----------------
__global__ void f2b_kernel(const float* __restrict__ s, ushort* __restrict__ d, int n) {
    int i = blockIdx.x * 256 + threadIdx.x;
    if (i < n) d[i] = f2b(s[i]);
}

// ---------------- embedding gather -> x0 [S][B][E] bf16 ----------------
__global__ void embed_kernel(const int* __restrict__ tok, const float* __restrict__ emb,
                             ushort* __restrict__ x0) {
    int row = blockIdx.x;
    int t = row >> 9, b = row & 511;
    int tk = tok[b * 128 + t];
    x0[(size_t)row * 256 + threadIdx.x] = f2b(emb[(size_t)tk * 256 + threadIdx.x]);
}

// ---------------- bf16 NT GEMM (m97-style): C[m][n] = A[m][:]·Bw[n][:] + bias ----------------
__global__ __launch_bounds__(256) void gemm_bias_kernel(
    const ushort* __restrict__ A, const ushort* __restrict__ Bw,
    const float* __restrict__ bias0, const float* __restrict__ bias1,
    ushort* __restrict__ C, int M, int N, int K) {
    __shared__ ushort la[128 * 32];
    __shared__ ushort lb[128 * 32];
    const int tid = threadIdx.x;
    const int wave = tid >> 6, lane = tid & 63;
    const int ntn = N >> 7;
    const int tm = blockIdx.x / ntn, tn = blockIdx.x % ntn;
    const int m0 = tm << 7, n0 = tn << 7;
    const int wm = (wave >> 1) * 64, wn = (wave & 1) * 64;
    f32x4 acc[4][4] = {};
    const int nks = K >> 5;
    const int srow = tid >> 2, scol = (tid & 3) * 8;
    for (int ks = 0; ks < nks; ++ks) {
        const int k0 = ks << 5;
#pragma unroll
        for (int r = 0; r < 2; ++r) {
            gload_lds16(A + (size_t)(m0 + r * 64 + srow) * K + k0 + scol, &la[r * 2048 + wave * 512]);
            gload_lds16(Bw + (size_t)(n0 + r * 64 + srow) * K + k0 + scol, &lb[r * 2048 + wave * 512]);
        }
        __syncthreads();
        bf16x8 af[4], bfr[4];
#pragma unroll
        for (int i = 0; i < 4; ++i)
            af[i] = *(const bf16x8*)&la[(wm + i * 16 + (lane & 15)) * 32 + (lane >> 4) * 8];
#pragma unroll
        for (int i = 0; i < 4; ++i)
            bfr[i] = *(const bf16x8*)&lb[(wn + i * 16 + (lane & 15)) * 32 + (lane >> 4) * 8];
#pragma unroll
        for (int mi = 0; mi < 4; ++mi)
#pragma unroll
            for (int ni = 0; ni < 4; ++ni)
                acc[mi][ni] = __builtin_amdgcn_mfma_f32_16x16x32_bf16(af[mi], bfr[ni], acc[mi][ni], 0, 0, 0);
        __syncthreads();
    }
#pragma unroll
    for (int mi = 0; mi < 4; ++mi) {
        int row = m0 + wm + mi * 16 + ((lane >> 4) << 2);
#pragma unroll
        for (int j = 0; j < 4; ++j) {
#pragma unroll
            for (int ni = 0; ni < 4; ++ni) {
                int col = n0 + wn + ni * 16 + (lane & 15);
                C[(size_t)(row + j) * N + col] = f2b(acc[mi][ni][j] + bias0[col] + bias1[col]);
            }
        }
    }
}

// ---------------- batch-independent LSTM chunk: 32 blocks x 16 batch rows ----------------
// Each block owns 16 batch rows, computes ALL 2048 gates for them each step.
// h tile in LDS (XOR-swizzled), c in VGPRs, Whh streamed from L2 per step.
// ZERO inter-block communication.
__global__ __launch_bounds__(512, 2) void lstm_chunk_kernel(
    const ushort* __restrict__ xpj,   // [32][512][2048] bf16 (x-projections incl. biases)
    const ushort* __restrict__ Whh,   // [2048][512] bf16
    ushort* __restrict__ hs,          // [128][512][512] bf16 (layer history)
    float* __restrict__ cstate,       // [512][512] f32 (chunk-boundary carry)
    float* __restrict__ hT, float* __restrict__ cT,
    int t0) {
    // xl: double-buffered xpj tile [16 rows][2048 gates], row stride padded to 2056 ushorts
    // hp: h tile [16 rows][512], row stride 528 ushorts (1056B, 16B-aligned), 16B-chunk XOR swizzle
    __shared__ ushort xl[2][16 * 2056];  // 131584 B
    __shared__ ushort hp[16 * 528];      // 16896 B
    const int tid = threadIdx.x;
    const int w = tid >> 6, lane = tid & 63;
    const int l15 = lane & 15, lh = lane >> 4;
    const int b0 = blockIdx.x << 4;

    // uniform Whh tile base pointers: wave w covers h-cols w*64..w*64+63 (4 quads), all 4 gates
    const ushort* tb[4][4];
#pragma unroll
    for (int qd = 0; qd < 4; ++qd)
#pragma unroll
        for (int g = 0; g < 4; ++g)
            tb[qd][g] = Whh + (size_t)(w * 64 + qd * 16 + g * 512) * 512;
    const int laneoff = l15 * 512 + lh * 8;

    // c-state: creg[qd*4+j] for row=lh*4+j, col=w*64+qd*16+l15
    float creg[16];
#pragma unroll
    for (int qd = 0; qd < 4; ++qd)
#pragma unroll
        for (int j = 0; j < 4; ++j) {
            const int row = lh * 4 + j, col = w * 64 + qd * 16 + l15;
            creg[qd * 4 + j] = (t0 > 0) ? cstate[(size_t)(b0 + row) * 512 + col] : 0.f;
        }

    // prologue: stage h(t0-1) into hp (swizzled) from previous chunk's output
    if (t0 > 0) {
        const ushort* hsrc = hs + (size_t)(t0 - 1) * 262144 + (size_t)b0 * 512;
        for (int i = tid; i < 1024; i += 512) {
            const int r = i >> 6, cc = i & 63;
            uint4 v = *(const uint4*)(hsrc + r * 512 + cc * 8);
            *(uint4*)&hp[r * 528 + ((cc ^ (r & 7)) << 3)] = v;
        }
    }
    // prologue: stage xl[0] (tt=0)
#pragma unroll
    for (int i = 0; i < 8; ++i) {
        const int ck = i * 8 + w, r = ck >> 2, c = ck & 3;
        gload_lds16(xpj + (size_t)(b0 + r) * 2048 + c * 512 + lane * 8,
                    &xl[0][r * 2056 + c * 512]);
    }
    __syncthreads();

    for (int tt = 0; tt < 32; ++tt) {
        const int t = t0 + tt;
        const int cur = tt & 1;
        // A-frags (h[t-1]) from LDS
        bf16x8 A[16];
        if (t > 0) {
#pragma unroll
            for (int ks = 0; ks < 16; ++ks)
                A[ks] = *(const bf16x8*)&hp[l15 * 528 + (((ks * 4 + lh) ^ (l15 & 7)) << 3)];
        }
        __syncthreads();  // bar1: all A-frags read -> hp writable; xl[cur] staged & drained
        // stage next step's xpj while MFMA runs
        if (tt < 31) {
            const ushort* xt = xpj + (size_t)(tt + 1) * 1048576;
#pragma unroll
            for (int i = 0; i < 8; ++i) {
                const int ck = i * 8 + w, r = ck >> 2, c = ck & 3;
                gload_lds16(xt + (size_t)(b0 + r) * 2048 + c * 512 + lane * 8,
                            &xl[cur ^ 1][r * 2056 + c * 512]);
            }
        }
        // MFMA: gates = h @ Whh^T  (B-frags streamed from L2, uniform base + imm offsets)
        f32x4 acc[4][4] = {};
        if (t > 0) {
#pragma unroll
            for (int qd = 0; qd < 4; ++qd)
#pragma unroll
                for (int g = 0; g < 4; ++g) {
                    const ushort* p = tb[qd][g] + laneoff;
#pragma unroll
                    for (int ks = 0; ks < 16; ++ks) {
                        bf16x8 B = *(const bf16x8*)(p + ks * 32);
                        acc[qd][g] =
                            __builtin_amdgcn_mfma_f32_16x16x32_bf16(A[ks], B, acc[qd][g], 0, 0, 0);
                    }
                }
        }
        // elementwise LSTM cell
        ushort* hout = hs + (size_t)t * 262144;
#pragma unroll
        for (int qd = 0; qd < 4; ++qd) {
            const int col = w * 64 + qd * 16 + l15;
#pragma unroll
            for (int j = 0; j < 4; ++j) {
                const int row = lh * 4 + j;
                const int xb = row * 2056 + col;
                float gi = acc[qd][0][j] + b2f(xl[cur][xb]);
                float gf = acc[qd][1][j] + b2f(xl[cur][xb + 512]);
                float gg = acc[qd][2][j] + b2f(xl[cur][xb + 1024]);
                float go = acc[qd][3][j] + b2f(xl[cur][xb + 1536]);
                float ig = fsig(gi), fg = fsig(gf), gv = ftanh(gg), og = fsig(go);
                float cn = fg * creg[qd * 4 + j] + ig * gv;
                float hn = og * ftanh(cn);
                creg[qd * 4 + j] = cn;
                const ushort hb = f2b(hn);
                hp[row * 528 + (((col >> 3) ^ (row & 7)) << 3) + (col & 7)] = hb;
                const size_t ci = (size_t)(b0 + row) * 512 + col;
                hout[ci] = hb;
                if (t == 127) { hT[ci] = hn; cT[ci] = cn; }
            }
        }
        __syncthreads();  // bar2: h[t] complete in LDS; next xpj stage drained
    }
    // persist c for next chunk
#pragma unroll
    for (int qd = 0; qd < 4; ++qd)
#pragma unroll
        for (int j = 0; j < 4; ++j) {
            const int row = lh * 4 + j, col = w * 64 + qd * 16 + l15;
            cstate[(size_t)(b0 + row) * 512 + col] = creg[qd * 4 + j];
        }
}

// ---------------- output projection ----------------
__global__ __launch_bounds__(256) void outproj_kernel(
    const ushort* __restrict__ hs, const float* __restrict__ Wout,
    const float* __restrict__ bout, float* __restrict__ out) {
    __shared__ ushort lh[32 * 512];
    const int tid = threadIdx.x;
    const size_t r0 = (size_t)blockIdx.x * 32;
    const uint4* gs = (const uint4*)(hs + r0 * 512);
    uint4* ls = (uint4*)lh;
    for (int i = tid; i < 2048; i += 256) ls[i] = gs[i];
    __syncthreads();
    const int rg = tid & 7, vg = tid >> 3;
    float acc[4][2] = {};
    for (int k8 = 0; k8 < 64; ++k8) {
        float hf[4][8];
#pragma unroll
        for (int rr = 0; rr < 4; ++rr) {
            bf16x8 hv = *(const bf16x8*)&lh[(rg * 4 + rr) * 512 + k8 * 8];
#pragma unroll
            for (int j = 0; j < 8; ++j) hf[rr][j] = b2f((ushort)hv[j]);
        }
#pragma unroll
        for (int vi = 0; vi < 2; ++vi) {
            int v = vg + vi * 32;
            if (v < 37) {
                const float* wp = Wout + (size_t)v * 512 + k8 * 8;
                float4 w0 = *(const float4*)wp;
                float4 w1 = *(const float4*)(wp + 4);
                float wv[8] = {w0.x, w0.y, w0.z, w0.w, w1.x, w1.y, w1.z, w1.w};
#pragma unroll
                for (int rr = 0; rr < 4; ++rr) {
                    float s = 0.f;
#pragma unroll
                    for (int j = 0; j < 8; ++j) s += hf[rr][j] * wv[j];
                    acc[rr][vi] += s;
                }
            }
        }
    }
#pragma unroll
    for (int vi = 0; vi < 2; ++vi) {
        int v = vg + vi * 32;
        if (v < 37) {
#pragma unroll
            for (int rr = 0; rr < 4; ++rr) {
                size_t r = r0 + rg * 4 + rr;
                int t = (int)(r >> 9), b = (int)(r & 511);
                out[((size_t)b * 128 + t) * 37 + v] = acc[rr][vi] + bout[v];
            }
        }
    }
}

extern "C" void kernel_launch(void* const* d_in, const int* in_sizes, int n_in,
                              void* d_out, int out_size, void* d_ws, size_t ws_size,
                              hipStream_t stream) {
    (void)in_sizes; (void)n_in; (void)out_size; (void)ws_size;
    const int* tokens = (const int*)d_in[0];
    const float* emb = (const float*)d_in[1];
    const float* Wih_f[3] = {(const float*)d_in[2], (const float*)d_in[6], (const float*)d_in[10]};
    const float* Whh_f[3] = {(const float*)d_in[3], (const float*)d_in[7], (const float*)d_in[11]};
    const float* bih[3] = {(const float*)d_in[4], (const float*)d_in[8], (const float*)d_in[12]};
    const float* bhh[3] = {(const float*)d_in[5], (const float*)d_in[9], (const float*)d_in[13]};
    const float* Wout = (const float*)d_in[14];
    const float* bout = (const float*)d_in[15];
    float* out = (float*)d_out;

    char* ws = (char*)d_ws;
    size_t off = 0;
    auto take = [&](size_t nb) -> void* {
        void* p = ws + off;
        off = (off + nb + 255) & ~(size_t)255;
        return p;
    };
    ushort* x0 = (ushort*)take((size_t)128 * 512 * 256 * 2);   // 16MB  [S][B][E]
    ushort* hsA = (ushort*)take((size_t)128 * 512 * 512 * 2);  // 64MB  [S][B][H]
    ushort* hsB = (ushort*)take((size_t)128 * 512 * 512 * 2);  // 64MB
    ushort* xpj = (ushort*)take((size_t)32 * 512 * 2048 * 2);  // 64MB  chunk [32][B][4H]
    float* cst = (float*)take((size_t)512 * 512 * 4);          // 1MB
    ushort* wih[3];
    wih[0] = (ushort*)take((size_t)2048 * 256 * 2);
    wih[1] = (ushort*)take((size_t)2048 * 512 * 2);
    wih[2] = (ushort*)take((size_t)2048 * 512 * 2);
    ushort* whh[3];
    for (int l = 0; l < 3; ++l) whh[l] = (ushort*)take((size_t)2048 * 512 * 2);

    f2b_kernel<<<2048, 256, 0, stream>>>(Wih_f[0], wih[0], 2048 * 256);
    f2b_kernel<<<4096, 256, 0, stream>>>(Wih_f[1], wih[1], 2048 * 512);
    f2b_kernel<<<4096, 256, 0, stream>>>(Wih_f[2], wih[2], 2048 * 512);
    for (int l = 0; l < 3; ++l)
        f2b_kernel<<<4096, 256, 0, stream>>>(Whh_f[l], whh[l], 2048 * 512);

    embed_kernel<<<65536, 256, 0, stream>>>(tokens, emb, x0);

    float* hTbase = out + 2424832;
    float* cTbase = out + 2424832 + 786432;
    const ushort* src = x0;
    ushort* hs_out = hsA;
    for (int l = 0; l < 3; ++l) {
        int K = (l == 0) ? 256 : 512;
        hs_out = (l == 1) ? hsB : hsA;
        for (int ch = 0; ch < 4; ++ch) {
            gemm_bias_kernel<<<2048, 256, 0, stream>>>(
                src + (size_t)ch * 16384 * K, wih[l], bih[l], bhh[l], xpj, 16384, 2048, K);
            lstm_chunk_kernel<<<32, 512, 0, stream>>>(
                xpj, whh[l], hs_out, cst,
                hTbase + (size_t)l * 262144, cTbase + (size_t)l * 262144, ch * 32);
        }
        src = hs_out;
    }
    outproj_kernel<<<2048, 256, 0, stream>>>(hs_out, Wout, bout, out);
}

// Round 5
// 3172.560 us; speedup vs baseline: 8.0799x; 8.0799x over previous
//
#include <hip/hip_runtime.h>

typedef __attribute__((ext_vector_type(4))) float f32x4;
typedef __attribute__((ext_vector_type(8))) short bf16x8;

#define DEV __device__ __forceinline__

DEV float b2f(ushort u) { return __uint_as_float(((uint)u) << 16); }
DEV ushort f2b(float f) {
    uint u = __float_as_uint(f);
    return (ushort)((u + 0x7fffu + ((u >> 16) & 1u)) >> 16);  // RNE
}
DEV float fsig(float x) {
    x = fminf(fmaxf(x, -30.f), 30.f);
    return 1.f / (1.f + __expf(-x));
}
DEV float ftanh(float x) {
    x = fminf(fmaxf(x, -15.f), 15.f);
    float e = __expf(2.f * x);
    return (e - 1.f) / (e + 1.f);
}
DEV void gload_lds16(const void* g, void* l) {
    __builtin_amdgcn_global_load_lds(
        (const __attribute__((address_space(1))) void*)g,
        (__attribute__((address_space(3))) void*)l, 16, 0, 0);
}
// staging load, SC0 only: bypass L1, may hit/allocate local (XCD) L2.
DEV void gload_lds16_l2(const void* g, void* l) {
    __builtin_amdgcn_global_load_lds(
        (const __attribute__((address_space(1))) void*)g,
        (__attribute__((address_space(3))) void*)l, 16, 0, 1);
}
// device-coherent write-through 4B store (updates local L2 clean + L3 truth)
DEV void store_sc_u32(uint* p, uint v) {
    asm volatile("global_store_dword %0, %1, off sc0 sc1" :: "v"(p), "v"(v) : "memory");
}
// L2-scope 4B load (bypass L1 only)
DEV uint load_l2_u32(const uint* p) {
    uint v;
    asm volatile("global_load_dword %0, %1, off sc0\n\ts_waitcnt vmcnt(0)"
                 : "=v"(v) : "v"(p) : "memory");
    return v;
}
// device-scope 4B load (bypass L1+L2 -> L3 truth)
DEV uint load_sc_u32(const uint* p) {
    uint v;
    asm volatile("global_load_dword %0, %1, off sc0 sc1\n\ts_waitcnt vmcnt(0)"
                 : "=v"(v) : "v"(p) : "memory");
    return v;
}

// ---------------- f32 -> bf16 weight conversion ----------------
__global__ void f2b_kernel(const float* __restrict__ s, ushort* __restrict__ d, int n) {
    int i = blockIdx.x * 256 + threadIdx.x;
    if (i < n) d[i] = f2b(s[i]);
}

// ---------------- embedding gather -> x0 [S][B][E] bf16 ----------------
__global__ void embed_kernel(const int* __restrict__ tok, const float* __restrict__ emb,
                             ushort* __restrict__ x0) {
    int row = blockIdx.x;
    int t = row >> 9, b = row & 511;
    int tk = tok[b * 128 + t];
    x0[(size_t)row * 256 + threadIdx.x] = f2b(emb[(size_t)tk * 256 + threadIdx.x]);
}

// ---------------- bf16 NT GEMM (m97-style): C[m][n] = A[m][:]·Bw[n][:] + bias ----------------
__global__ __launch_bounds__(256) void gemm_bias_kernel(
    const ushort* __restrict__ A, const ushort* __restrict__ Bw,
    const float* __restrict__ bias0, const float* __restrict__ bias1,
    ushort* __restrict__ C, int M, int N, int K) {
    __shared__ ushort la[128 * 32];
    __shared__ ushort lb[128 * 32];
    const int tid = threadIdx.x;
    const int wave = tid >> 6, lane = tid & 63;
    const int ntn = N >> 7;
    const int tm = blockIdx.x / ntn, tn = blockIdx.x % ntn;
    const int m0 = tm << 7, n0 = tn << 7;
    const int wm = (wave >> 1) * 64, wn = (wave & 1) * 64;
    f32x4 acc[4][4] = {};
    const int nks = K >> 5;
    const int srow = tid >> 2, scol = (tid & 3) * 8;
    for (int ks = 0; ks < nks; ++ks) {
        const int k0 = ks << 5;
#pragma unroll
        for (int r = 0; r < 2; ++r) {
            gload_lds16(A + (size_t)(m0 + r * 64 + srow) * K + k0 + scol, &la[r * 2048 + wave * 512]);
            gload_lds16(Bw + (size_t)(n0 + r * 64 + srow) * K + k0 + scol, &lb[r * 2048 + wave * 512]);
        }
        __syncthreads();
        bf16x8 af[4], bfr[4];
#pragma unroll
        for (int i = 0; i < 4; ++i)
            af[i] = *(const bf16x8*)&la[(wm + i * 16 + (lane & 15)) * 32 + (lane >> 4) * 8];
#pragma unroll
        for (int i = 0; i < 4; ++i)
            bfr[i] = *(const bf16x8*)&lb[(wn + i * 16 + (lane & 15)) * 32 + (lane >> 4) * 8];
#pragma unroll
        for (int mi = 0; mi < 4; ++mi)
#pragma unroll
            for (int ni = 0; ni < 4; ++ni)
                acc[mi][ni] = __builtin_amdgcn_mfma_f32_16x16x32_bf16(af[mi], bfr[ni], acc[mi][ni], 0, 0, 0);
        __syncthreads();
    }
#pragma unroll
    for (int mi = 0; mi < 4; ++mi) {
        int row = m0 + wm + mi * 16 + ((lane >> 4) << 2);
#pragma unroll
        for (int j = 0; j < 4; ++j) {
#pragma unroll
            for (int ni = 0; ni < 4; ++ni) {
                int col = n0 + wn + ni * 16 + (lane & 15);
                C[(size_t)(row + j) * N + col] = f2b(acc[mi][ni][j] + bias0[col] + bias1[col]);
            }
        }
    }
}

// ---------------- persistent LSTM chunk: 32 timesteps, XCD-local group barrier ----------------
// grid 256 = 8 batch-groups x 32 h-slices. grp = bid & 7 -> all 32 slice-blocks of a group land
// on ONE XCD (round-robin dispatch), so h exchange + flags run at local-L2 latency.
// Data correctness does NOT depend on the mapping (write-through stores + read-once lines);
// flag polls fall back to device scope every 16 spins so a broken mapping degrades, not hangs.
__global__ __launch_bounds__(256) void lstm_chunk_kernel(
    const ushort* __restrict__ xpj,   // [32][512][2048] bf16 (x-projections incl. biases)
    const ushort* __restrict__ Whh,   // [2048][512] bf16
    ushort* __restrict__ hs,          // [128][512][512] bf16 (layer history)
    float* __restrict__ cstate,       // [512][512] f32
    float* __restrict__ hT, float* __restrict__ cT,
    uint* __restrict__ bar,           // this launch: 8 groups x 32 slices x 16 uints (zeroed)
    int t0) {
    __shared__ ushort hp[64 * 512];   // 64KB staged hprev tile (16B-block XOR swizzled)
    __shared__ float gbuf[4][64][16]; // 16KB gate partials
    const int tid = threadIdx.x;
    const int wave = tid >> 6, lane = tid & 63;
    const int grp = blockIdx.x & 7;   // XCD-local group
    const int hsl = blockIdx.x >> 3;  // h-slice 0..31
    const int b0 = grp << 6, h0 = hsl << 4;
    uint* gflags = bar + grp * 512;
    uint* myflag = gflags + hsl * 16;

    // one-time acquire: drop any stale L2 lines from previous dispatches/replays
    __threadfence();

    // Whh fragments for this wave's gate: 16 K-steps x bf16x8 (64 VGPRs)
    bf16x8 Bfr[16];
    const ushort* wb = Whh + ((size_t)(wave * 512 + h0 + (lane & 15))) * 512 + (lane >> 4) * 8;
#pragma unroll
    for (int ks = 0; ks < 16; ++ks) Bfr[ks] = *(const bf16x8*)(wb + ks * 32);

    // c-state registers (2 adjacent h per slot pair)
    float creg[4];
#pragma unroll
    for (int i = 0; i < 2; ++i) {
        const int e2 = i * 512 + tid * 2;
        const size_t ci = (size_t)(b0 + (e2 >> 4)) * 512 + h0 + (e2 & 15);
        if (t0 > 0) {
            float2 cv = *(const float2*)&cstate[ci];
            creg[2 * i] = cv.x; creg[2 * i + 1] = cv.y;
        } else {
            creg[2 * i] = 0.f; creg[2 * i + 1] = 0.f;
        }
    }

    for (int tt = 0; tt < 32; ++tt) {
        const int t = t0 + tt;
        // prefetch this step's xpj gate pairs (independent of peers -> hides under spin)
        uint xq[2][4];
        const ushort* xt = xpj + (size_t)tt * 1048576;
#pragma unroll
        for (int i = 0; i < 2; ++i) {
            const int e2 = i * 512 + tid * 2;
            const uint* xb = (const uint*)(xt + (size_t)(b0 + (e2 >> 4)) * 2048 + h0 + (e2 & 15));
            xq[i][0] = xb[0]; xq[i][1] = xb[256]; xq[i][2] = xb[512]; xq[i][3] = xb[768];
        }
        // wait for all 32 slice-blocks of this group to have produced h[t-1]
        if (tt > 0) {
            if (wave == 0) {
                const uint* fp = gflags + ((lane & 31) << 4);
                const uint target = (uint)tt;
                int k = 0;
                for (;;) {
                    uint v = ((++k & 15) == 0) ? load_sc_u32(fp) : load_l2_u32(fp);
                    if (__all(v >= target)) break;
                    __builtin_amdgcn_s_sleep(1);
                }
            }
            __syncthreads();
        }
        f32x4 acc[4] = {};
        if (t > 0) {
            const ushort* hprev = hs + (size_t)(t - 1) * 262144;
#pragma unroll
            for (int rr = 0; rr < 16; ++rr) {
                const int row = rr * 4 + wave;
                gload_lds16_l2(hprev + (size_t)(b0 + row) * 512 + ((lane ^ (row & 7)) * 8),
                               &hp[row * 512]);
            }
            __syncthreads();
#pragma unroll
            for (int ks = 0; ks < 16; ++ks) {
#pragma unroll
                for (int mi = 0; mi < 4; ++mi) {
                    const int row = mi * 16 + (lane & 15);
                    const int c16 = (ks * 4 + (lane >> 4)) ^ (row & 7);
                    bf16x8 af = *(const bf16x8*)&hp[row * 512 + c16 * 8];
                    acc[mi] = __builtin_amdgcn_mfma_f32_16x16x32_bf16(af, Bfr[ks], acc[mi], 0, 0, 0);
                }
            }
        }
#pragma unroll
        for (int mi = 0; mi < 4; ++mi) {
            const int rloc = mi * 16 + ((lane >> 4) << 2);
#pragma unroll
            for (int j = 0; j < 4; ++j) gbuf[wave][rloc + j][lane & 15] = acc[mi][j];
        }
        __syncthreads();
        ushort* hout = hs + (size_t)t * 262144;
#pragma unroll
        for (int i = 0; i < 2; ++i) {
            const int e2 = i * 512 + tid * 2;
            const int b = e2 >> 4, hh = e2 & 15;
            float2 gI = *(const float2*)&gbuf[0][b][hh];
            float2 gF = *(const float2*)&gbuf[1][b][hh];
            float2 gG = *(const float2*)&gbuf[2][b][hh];
            float2 gO = *(const float2*)&gbuf[3][b][hh];
            float i0 = fsig(gI.x + b2f((ushort)(xq[i][0] & 0xffff)));
            float i1 = fsig(gI.y + b2f((ushort)(xq[i][0] >> 16)));
            float f0 = fsig(gF.x + b2f((ushort)(xq[i][1] & 0xffff)));
            float f1 = fsig(gF.y + b2f((ushort)(xq[i][1] >> 16)));
            float g0 = ftanh(gG.x + b2f((ushort)(xq[i][2] & 0xffff)));
            float g1 = ftanh(gG.y + b2f((ushort)(xq[i][2] >> 16)));
            float o0 = fsig(gO.x + b2f((ushort)(xq[i][3] & 0xffff)));
            float o1 = fsig(gO.y + b2f((ushort)(xq[i][3] >> 16)));
            float c0 = f0 * creg[2 * i] + i0 * g0;
            float c1 = f1 * creg[2 * i + 1] + i1 * g1;
            float h0v = o0 * ftanh(c0);
            float h1v = o1 * ftanh(c1);
            creg[2 * i] = c0; creg[2 * i + 1] = c1;
            const size_t ci = (size_t)(b0 + b) * 512 + h0 + hh;
            store_sc_u32((uint*)(hout + ci), (uint)f2b(h0v) | ((uint)f2b(h1v) << 16));
            if (t == 127) {
                *(float2*)&hT[ci] = make_float2(h0v, h1v);
                *(float2*)&cT[ci] = make_float2(c0, c1);
            }
        }
        if (tt < 31) {
            asm volatile("s_waitcnt vmcnt(0)" ::: "memory");  // h write-through complete
            __syncthreads();                                   // whole block done
            if (tid == 0) store_sc_u32(myflag, (uint)(tt + 1));
        }
    }
    // persist c for next chunk (cross-kernel visibility via dispatch-boundary release)
#pragma unroll
    for (int i = 0; i < 2; ++i) {
        const int e2 = i * 512 + tid * 2;
        const size_t ci = (size_t)(b0 + (e2 >> 4)) * 512 + h0 + (e2 & 15);
        *(float2*)&cstate[ci] = make_float2(creg[2 * i], creg[2 * i + 1]);
    }
}

// ---------------- output projection ----------------
__global__ __launch_bounds__(256) void outproj_kernel(
    const ushort* __restrict__ hs, const float* __restrict__ Wout,
    const float* __restrict__ bout, float* __restrict__ out) {
    __shared__ ushort lh[32 * 512];
    const int tid = threadIdx.x;
    const size_t r0 = (size_t)blockIdx.x * 32;
    const uint4* gs = (const uint4*)(hs + r0 * 512);
    uint4* ls = (uint4*)lh;
    for (int i = tid; i < 2048; i += 256) ls[i] = gs[i];
    __syncthreads();
    const int rg = tid & 7, vg = tid >> 3;
    float acc[4][2] = {};
    for (int k8 = 0; k8 < 64; ++k8) {
        float hf[4][8];
#pragma unroll
        for (int rr = 0; rr < 4; ++rr) {
            bf16x8 hv = *(const bf16x8*)&lh[(rg * 4 + rr) * 512 + k8 * 8];
#pragma unroll
            for (int j = 0; j < 8; ++j) hf[rr][j] = b2f((ushort)hv[j]);
        }
#pragma unroll
        for (int vi = 0; vi < 2; ++vi) {
            int v = vg + vi * 32;
            if (v < 37) {
                const float* wp = Wout + (size_t)v * 512 + k8 * 8;
                float4 w0 = *(const float4*)wp;
                float4 w1 = *(const float4*)(wp + 4);
                float wv[8] = {w0.x, w0.y, w0.z, w0.w, w1.x, w1.y, w1.z, w1.w};
#pragma unroll
                for (int rr = 0; rr < 4; ++rr) {
                    float s = 0.f;
#pragma unroll
                    for (int j = 0; j < 8; ++j) s += hf[rr][j] * wv[j];
                    acc[rr][vi] += s;
                }
            }
        }
    }
#pragma unroll
    for (int vi = 0; vi < 2; ++vi) {
        int v = vg + vi * 32;
        if (v < 37) {
#pragma unroll
            for (int rr = 0; rr < 4; ++rr) {
                size_t r = r0 + rg * 4 + rr;
                int t = (int)(r >> 9), b = (int)(r & 511);
                out[((size_t)b * 128 + t) * 37 + v] = acc[rr][vi] + bout[v];
            }
        }
    }
}

extern "C" void kernel_launch(void* const* d_in, const int* in_sizes, int n_in,
                              void* d_out, int out_size, void* d_ws, size_t ws_size,
                              hipStream_t stream) {
    (void)in_sizes; (void)n_in; (void)out_size; (void)ws_size;
    const int* tokens = (const int*)d_in[0];
    const float* emb = (const float*)d_in[1];
    const float* Wih_f[3] = {(const float*)d_in[2], (const float*)d_in[6], (const float*)d_in[10]};
    const float* Whh_f[3] = {(const float*)d_in[3], (const float*)d_in[7], (const float*)d_in[11]};
    const float* bih[3] = {(const float*)d_in[4], (const float*)d_in[8], (const float*)d_in[12]};
    const float* bhh[3] = {(const float*)d_in[5], (const float*)d_in[9], (const float*)d_in[13]};
    const float* Wout = (const float*)d_in[14];
    const float* bout = (const float*)d_in[15];
    float* out = (float*)d_out;

    char* ws = (char*)d_ws;
    size_t off = 0;
    auto take = [&](size_t nb) -> void* {
        void* p = ws + off;
        off = (off + nb + 255) & ~(size_t)255;
        return p;
    };
    ushort* x0 = (ushort*)take((size_t)128 * 512 * 256 * 2);   // 16MB  [S][B][E]
    ushort* hsA = (ushort*)take((size_t)128 * 512 * 512 * 2);  // 64MB  [S][B][H]
    ushort* hsB = (ushort*)take((size_t)128 * 512 * 512 * 2);  // 64MB
    ushort* xpj = (ushort*)take((size_t)32 * 512 * 2048 * 2);  // 64MB  chunk [32][B][4H]
    float* cst = (float*)take((size_t)512 * 512 * 4);          // 1MB
    ushort* wih[3];
    wih[0] = (ushort*)take((size_t)2048 * 256 * 2);
    wih[1] = (ushort*)take((size_t)2048 * 512 * 2);
    wih[2] = (ushort*)take((size_t)2048 * 512 * 2);
    ushort* whh[3];
    for (int l = 0; l < 3; ++l) whh[l] = (ushort*)take((size_t)2048 * 512 * 2);
    uint* barbase = (uint*)take((size_t)12 * 4096 * 4);  // per-launch flag regions

    hipMemsetAsync(barbase, 0, (size_t)12 * 4096 * 4, stream);

    f2b_kernel<<<2048, 256, 0, stream>>>(Wih_f[0], wih[0], 2048 * 256);
    f2b_kernel<<<4096, 256, 0, stream>>>(Wih_f[1], wih[1], 2048 * 512);
    f2b_kernel<<<4096, 256, 0, stream>>>(Wih_f[2], wih[2], 2048 * 512);
    for (int l = 0; l < 3; ++l)
        f2b_kernel<<<4096, 256, 0, stream>>>(Whh_f[l], whh[l], 2048 * 512);

    embed_kernel<<<65536, 256, 0, stream>>>(tokens, emb, x0);

    float* hTbase = out + 2424832;
    float* cTbase = out + 2424832 + 786432;
    const ushort* src = x0;
    ushort* hs_out = hsA;
    for (int l = 0; l < 3; ++l) {
        int K = (l == 0) ? 256 : 512;
        hs_out = (l == 1) ? hsB : hsA;
        for (int ch = 0; ch < 4; ++ch) {
            gemm_bias_kernel<<<2048, 256, 0, stream>>>(
                src + (size_t)ch * 16384 * K, wih[l], bih[l], bhh[l], xpj, 16384, 2048, K);
            lstm_chunk_kernel<<<256, 256, 0, stream>>>(
                xpj, whh[l], hs_out, cst,
                hTbase + (size_t)l * 262144, cTbase + (size_t)l * 262144,
                barbase + (size_t)(l * 4 + ch) * 4096, ch * 32);
        }
        src = hs_out;
    }
    outproj_kernel<<<2048, 256, 0, stream>>>(hs_out, Wout, bout, out);
}

// Round 6
// 2516.617 us; speedup vs baseline: 10.1858x; 1.2606x over previous
//
#include <hip/hip_runtime.h>

typedef __attribute__((ext_vector_type(4))) float f32x4;
typedef __attribute__((ext_vector_type(8))) short bf16x8;

#define DEV __device__ __forceinline__

DEV float b2f(ushort u) { return __uint_as_float(((uint)u) << 16); }
DEV ushort f2b(float f) {
    uint u = __float_as_uint(f);
    return (ushort)((u + 0x7fffu + ((u >> 16) & 1u)) >> 16);  // RNE
}
// clamp-free fast sigmoid/tanh: v_exp_f32 is 2^x; rcp handles inf -> 0
DEV float fsig(float x) {
    return __builtin_amdgcn_rcpf(1.f + __builtin_amdgcn_exp2f(-1.4426950408889634f * x));
}
DEV float ftanh(float x) {
    return 1.f - 2.f * __builtin_amdgcn_rcpf(__builtin_amdgcn_exp2f(2.885390081777927f * x) + 1.f);
}
DEV void gload_lds16(const void* g, void* l) {
    __builtin_amdgcn_global_load_lds(
        (const __attribute__((address_space(1))) void*)g,
        (__attribute__((address_space(3))) void*)l, 16, 0, 0);
}
// staging load, SC0 only: bypass L1, may hit/allocate local (XCD) L2.
DEV void gload_lds16_l2(const void* g, void* l) {
    __builtin_amdgcn_global_load_lds(
        (const __attribute__((address_space(1))) void*)g,
        (__attribute__((address_space(3))) void*)l, 16, 0, 1);
}
// device-coherent write-through 4B store
DEV void store_sc_u32(uint* p, uint v) {
    asm volatile("global_store_dword %0, %1, off sc0 sc1" :: "v"(p), "v"(v) : "memory");
}
// device-scope 4B load (bypass L1+L2 -> coherence point truth)
DEV uint load_sc_u32(const uint* p) {
    uint v;
    asm volatile("global_load_dword %0, %1, off sc0 sc1\n\ts_waitcnt vmcnt(0)"
                 : "=v"(v) : "v"(p) : "memory");
    return v;
}

// ---------------- f32 -> bf16 weight conversion ----------------
__global__ void f2b_kernel(const float* __restrict__ s, ushort* __restrict__ d, int n) {
    int i = blockIdx.x * 256 + threadIdx.x;
    if (i < n) d[i] = f2b(s[i]);
}

// ---------------- embedding gather -> x0 [S][B][E] bf16 ----------------
__global__ void embed_kernel(const int* __restrict__ tok, const float* __restrict__ emb,
                             ushort* __restrict__ x0) {
    int row = blockIdx.x;
    int t = row >> 9, b = row & 511;
    int tk = tok[b * 128 + t];
    x0[(size_t)row * 256 + threadIdx.x] = f2b(emb[(size_t)tk * 256 + threadIdx.x]);
}

// ---------------- bf16 NT GEMM (m97-style): C[m][n] = A[m][:]·Bw[n][:] + bias ----------------
__global__ __launch_bounds__(256) void gemm_bias_kernel(
    const ushort* __restrict__ A, const ushort* __restrict__ Bw,
    const float* __restrict__ bias0, const float* __restrict__ bias1,
    ushort* __restrict__ C, int M, int N, int K) {
    __shared__ ushort la[128 * 32];
    __shared__ ushort lb[128 * 32];
    const int tid = threadIdx.x;
    const int wave = tid >> 6, lane = tid & 63;
    const int ntn = N >> 7;
    const int tm = blockIdx.x / ntn, tn = blockIdx.x % ntn;
    const int m0 = tm << 7, n0 = tn << 7;
    const int wm = (wave >> 1) * 64, wn = (wave & 1) * 64;
    f32x4 acc[4][4] = {};
    const int nks = K >> 5;
    const int srow = tid >> 2, scol = (tid & 3) * 8;
    for (int ks = 0; ks < nks; ++ks) {
        const int k0 = ks << 5;
#pragma unroll
        for (int r = 0; r < 2; ++r) {
            gload_lds16(A + (size_t)(m0 + r * 64 + srow) * K + k0 + scol, &la[r * 2048 + wave * 512]);
            gload_lds16(Bw + (size_t)(n0 + r * 64 + srow) * K + k0 + scol, &lb[r * 2048 + wave * 512]);
        }
        __syncthreads();
        bf16x8 af[4], bfr[4];
#pragma unroll
        for (int i = 0; i < 4; ++i)
            af[i] = *(const bf16x8*)&la[(wm + i * 16 + (lane & 15)) * 32 + (lane >> 4) * 8];
#pragma unroll
        for (int i = 0; i < 4; ++i)
            bfr[i] = *(const bf16x8*)&lb[(wn + i * 16 + (lane & 15)) * 32 + (lane >> 4) * 8];
#pragma unroll
        for (int mi = 0; mi < 4; ++mi)
#pragma unroll
            for (int ni = 0; ni < 4; ++ni)
                acc[mi][ni] = __builtin_amdgcn_mfma_f32_16x16x32_bf16(af[mi], bfr[ni], acc[mi][ni], 0, 0, 0);
        __syncthreads();
    }
#pragma unroll
    for (int mi = 0; mi < 4; ++mi) {
        int row = m0 + wm + mi * 16 + ((lane >> 4) << 2);
#pragma unroll
        for (int j = 0; j < 4; ++j) {
#pragma unroll
            for (int ni = 0; ni < 4; ++ni) {
                int col = n0 + wn + ni * 16 + (lane & 15);
                C[(size_t)(row + j) * N + col] = f2b(acc[mi][ni][j] + bias0[col] + bias1[col]);
            }
        }
    }
}

// ---------------- persistent LSTM chunk: 32 timesteps, device-scope flag barrier ----------------
// grid 256 = 8 batch-groups (grp = bid&7, XCD-local for data staging) x 32 h-slices.
// Whh in registers. h exchange: sc0/sc1 write-through stores; staging reads sc0 (local L2 may hit).
// Flags: ALWAYS device-scope (sc0 sc1) — R5 showed sc0-only polls cache stale lines.
__global__ __launch_bounds__(256) void lstm_chunk_kernel(
    const ushort* __restrict__ xpj,   // [32][512][2048] bf16 (x-projections incl. biases)
    const ushort* __restrict__ Whh,   // [2048][512] bf16
    ushort* __restrict__ hs,          // [128][512][512] bf16 (layer history)
    float* __restrict__ cstate,       // [512][512] f32
    float* __restrict__ hT, float* __restrict__ cT,
    uint* __restrict__ bar,           // this launch: 8 groups x 32 slices x 16 uints (zeroed)
    int t0) {
    __shared__ ushort hp[64 * 512];    // 64KB staged hprev tile (16B-block XOR swizzled)
    __shared__ float gbuf[4][64][20];  // padded: bank = (b*20+hh)%32 varies with b
    const int tid = threadIdx.x;
    const int wave = tid >> 6, lane = tid & 63;
    const int grp = blockIdx.x & 7;   // XCD-local group
    const int hsl = blockIdx.x >> 3;  // h-slice 0..31
    const int b0 = grp << 6, h0 = hsl << 4;
    uint* gflags = bar + grp * 512;
    uint* myflag = gflags + hsl * 16;

    // one-time acquire: drop stale L2 lines from previous dispatches/replays
    __threadfence();

    // Whh fragments for this wave's gate: 16 K-steps x bf16x8 (64 VGPRs)
    bf16x8 Bfr[16];
    const ushort* wb = Whh + ((size_t)(wave * 512 + h0 + (lane & 15))) * 512 + (lane >> 4) * 8;
#pragma unroll
    for (int ks = 0; ks < 16; ++ks) Bfr[ks] = *(const bf16x8*)(wb + ks * 32);

    // c-state registers (2 adjacent h per slot pair)
    float creg[4];
#pragma unroll
    for (int i = 0; i < 2; ++i) {
        const int e2 = i * 512 + tid * 2;
        const size_t ci = (size_t)(b0 + (e2 >> 4)) * 512 + h0 + (e2 & 15);
        if (t0 > 0) {
            float2 cv = *(const float2*)&cstate[ci];
            creg[2 * i] = cv.x; creg[2 * i + 1] = cv.y;
        } else {
            creg[2 * i] = 0.f; creg[2 * i + 1] = 0.f;
        }
    }

    for (int tt = 0; tt < 32; ++tt) {
        const int t = t0 + tt;
        // prefetch this step's xpj gate pairs (hides under flag spin)
        uint xq[2][4];
        const ushort* xt = xpj + (size_t)tt * 1048576;
#pragma unroll
        for (int i = 0; i < 2; ++i) {
            const int e2 = i * 512 + tid * 2;
            const uint* xb = (const uint*)(xt + (size_t)(b0 + (e2 >> 4)) * 2048 + h0 + (e2 & 15));
            xq[i][0] = xb[0]; xq[i][1] = xb[256]; xq[i][2] = xb[512]; xq[i][3] = xb[768];
        }
        // wait for all 32 slice-blocks of this group to have produced h[t-1]
        if (tt > 0) {
            if (wave == 0) {
                const uint* fp = gflags + ((lane & 31) << 4);
                const uint target = (uint)tt;
                while (!__all(load_sc_u32(fp) >= target)) __builtin_amdgcn_s_sleep(1);
            }
            __syncthreads();
        }
        f32x4 acc[4] = {};
        if (t > 0) {
            const ushort* hprev = hs + (size_t)(t - 1) * 262144;
#pragma unroll
            for (int rr = 0; rr < 16; ++rr) {
                const int row = rr * 4 + wave;
                gload_lds16_l2(hprev + (size_t)(b0 + row) * 512 + ((lane ^ (row & 7)) * 8),
                               &hp[row * 512]);
            }
            __syncthreads();
#pragma unroll
            for (int ks = 0; ks < 16; ++ks) {
#pragma unroll
                for (int mi = 0; mi < 4; ++mi) {
                    const int row = mi * 16 + (lane & 15);
                    const int c16 = (ks * 4 + (lane >> 4)) ^ (row & 7);
                    bf16x8 af = *(const bf16x8*)&hp[row * 512 + c16 * 8];
                    acc[mi] = __builtin_amdgcn_mfma_f32_16x16x32_bf16(af, Bfr[ks], acc[mi], 0, 0, 0);
                }
            }
        }
#pragma unroll
        for (int mi = 0; mi < 4; ++mi) {
            const int rloc = mi * 16 + ((lane >> 4) << 2);
#pragma unroll
            for (int j = 0; j < 4; ++j) gbuf[wave][rloc + j][lane & 15] = acc[mi][j];
        }
        __syncthreads();
        ushort* hout = hs + (size_t)t * 262144;
#pragma unroll
        for (int i = 0; i < 2; ++i) {
            const int e2 = i * 512 + tid * 2;
            const int b = e2 >> 4, hh = e2 & 15;
            float2 gI = *(const float2*)&gbuf[0][b][hh];
            float2 gF = *(const float2*)&gbuf[1][b][hh];
            float2 gG = *(const float2*)&gbuf[2][b][hh];
            float2 gO = *(const float2*)&gbuf[3][b][hh];
            float i0 = fsig(gI.x + b2f((ushort)(xq[i][0] & 0xffff)));
            float i1 = fsig(gI.y + b2f((ushort)(xq[i][0] >> 16)));
            float f0 = fsig(gF.x + b2f((ushort)(xq[i][1] & 0xffff)));
            float f1 = fsig(gF.y + b2f((ushort)(xq[i][1] >> 16)));
            float g0 = ftanh(gG.x + b2f((ushort)(xq[i][2] & 0xffff)));
            float g1 = ftanh(gG.y + b2f((ushort)(xq[i][2] >> 16)));
            float o0 = fsig(gO.x + b2f((ushort)(xq[i][3] & 0xffff)));
            float o1 = fsig(gO.y + b2f((ushort)(xq[i][3] >> 16)));
            float c0 = f0 * creg[2 * i] + i0 * g0;
            float c1 = f1 * creg[2 * i + 1] + i1 * g1;
            float h0v = o0 * ftanh(c0);
            float h1v = o1 * ftanh(c1);
            creg[2 * i] = c0; creg[2 * i + 1] = c1;
            const size_t ci = (size_t)(b0 + b) * 512 + h0 + hh;
            store_sc_u32((uint*)(hout + ci), (uint)f2b(h0v) | ((uint)f2b(h1v) << 16));
            if (t == 127) {
                *(float2*)&hT[ci] = make_float2(h0v, h1v);
                *(float2*)&cT[ci] = make_float2(c0, c1);
            }
        }
        if (tt < 31) {
            asm volatile("s_waitcnt vmcnt(0)" ::: "memory");  // h write-through complete
            __syncthreads();                                   // whole block done
            if (tid == 0) store_sc_u32(myflag, (uint)(tt + 1));
        }
    }
    // persist c for next chunk
#pragma unroll
    for (int i = 0; i < 2; ++i) {
        const int e2 = i * 512 + tid * 2;
        const size_t ci = (size_t)(b0 + (e2 >> 4)) * 512 + h0 + (e2 & 15);
        *(float2*)&cstate[ci] = make_float2(creg[2 * i], creg[2 * i + 1]);
    }
}

// ---------------- output projection ----------------
__global__ __launch_bounds__(256) void outproj_kernel(
    const ushort* __restrict__ hs, const float* __restrict__ Wout,
    const float* __restrict__ bout, float* __restrict__ out) {
    __shared__ ushort lh[32 * 512];
    const int tid = threadIdx.x;
    const size_t r0 = (size_t)blockIdx.x * 32;
    const uint4* gs = (const uint4*)(hs + r0 * 512);
    uint4* ls = (uint4*)lh;
    for (int i = tid; i < 2048; i += 256) ls[i] = gs[i];
    __syncthreads();
    const int rg = tid & 7, vg = tid >> 3;
    float acc[4][2] = {};
    for (int k8 = 0; k8 < 64; ++k8) {
        float hf[4][8];
#pragma unroll
        for (int rr = 0; rr < 4; ++rr) {
            bf16x8 hv = *(const bf16x8*)&lh[(rg * 4 + rr) * 512 + k8 * 8];
#pragma unroll
            for (int j = 0; j < 8; ++j) hf[rr][j] = b2f((ushort)hv[j]);
        }
#pragma unroll
        for (int vi = 0; vi < 2; ++vi) {
            int v = vg + vi * 32;
            if (v < 37) {
                const float* wp = Wout + (size_t)v * 512 + k8 * 8;
                float4 w0 = *(const float4*)wp;
                float4 w1 = *(const float4*)(wp + 4);
                float wv[8] = {w0.x, w0.y, w0.z, w0.w, w1.x, w1.y, w1.z, w1.w};
#pragma unroll
                for (int rr = 0; rr < 4; ++rr) {
                    float s = 0.f;
#pragma unroll
                    for (int j = 0; j < 8; ++j) s += hf[rr][j] * wv[j];
                    acc[rr][vi] += s;
                }
            }
        }
    }
#pragma unroll
    for (int vi = 0; vi < 2; ++vi) {
        int v = vg + vi * 32;
        if (v < 37) {
#pragma unroll
            for (int rr = 0; rr < 4; ++rr) {
                size_t r = r0 + rg * 4 + rr;
                int t = (int)(r >> 9), b = (int)(r & 511);
                out[((size_t)b * 128 + t) * 37 + v] = acc[rr][vi] + bout[v];
            }
        }
    }
}

extern "C" void kernel_launch(void* const* d_in, const int* in_sizes, int n_in,
                              void* d_out, int out_size, void* d_ws, size_t ws_size,
                              hipStream_t stream) {
    (void)in_sizes; (void)n_in; (void)out_size; (void)ws_size;
    const int* tokens = (const int*)d_in[0];
    const float* emb = (const float*)d_in[1];
    const float* Wih_f[3] = {(const float*)d_in[2], (const float*)d_in[6], (const float*)d_in[10]};
    const float* Whh_f[3] = {(const float*)d_in[3], (const float*)d_in[7], (const float*)d_in[11]};
    const float* bih[3] = {(const float*)d_in[4], (const float*)d_in[8], (const float*)d_in[12]};
    const float* bhh[3] = {(const float*)d_in[5], (const float*)d_in[9], (const float*)d_in[13]};
    const float* Wout = (const float*)d_in[14];
    const float* bout = (const float*)d_in[15];
    float* out = (float*)d_out;

    char* ws = (char*)d_ws;
    size_t off = 0;
    auto take = [&](size_t nb) -> void* {
        void* p = ws + off;
        off = (off + nb + 255) & ~(size_t)255;
        return p;
    };
    ushort* x0 = (ushort*)take((size_t)128 * 512 * 256 * 2);   // 16MB  [S][B][E]
    ushort* hsA = (ushort*)take((size_t)128 * 512 * 512 * 2);  // 64MB  [S][B][H]
    ushort* hsB = (ushort*)take((size_t)128 * 512 * 512 * 2);  // 64MB
    ushort* xpj = (ushort*)take((size_t)32 * 512 * 2048 * 2);  // 64MB  chunk [32][B][4H]
    float* cst = (float*)take((size_t)512 * 512 * 4);          // 1MB
    ushort* wih[3];
    wih[0] = (ushort*)take((size_t)2048 * 256 * 2);
    wih[1] = (ushort*)take((size_t)2048 * 512 * 2);
    wih[2] = (ushort*)take((size_t)2048 * 512 * 2);
    ushort* whh[3];
    for (int l = 0; l < 3; ++l) whh[l] = (ushort*)take((size_t)2048 * 512 * 2);
    uint* barbase = (uint*)take((size_t)12 * 4096 * 4);  // per-launch flag regions

    hipMemsetAsync(barbase, 0, (size_t)12 * 4096 * 4, stream);

    f2b_kernel<<<2048, 256, 0, stream>>>(Wih_f[0], wih[0], 2048 * 256);
    f2b_kernel<<<4096, 256, 0, stream>>>(Wih_f[1], wih[1], 2048 * 512);
    f2b_kernel<<<4096, 256, 0, stream>>>(Wih_f[2], wih[2], 2048 * 512);
    for (int l = 0; l < 3; ++l)
        f2b_kernel<<<4096, 256, 0, stream>>>(Whh_f[l], whh[l], 2048 * 512);

    embed_kernel<<<65536, 256, 0, stream>>>(tokens, emb, x0);

    float* hTbase = out + 2424832;
    float* cTbase = out + 2424832 + 786432;
    const ushort* src = x0;
    ushort* hs_out = hsA;
    for (int l = 0; l < 3; ++l) {
        int K = (l == 0) ? 256 : 512;
        hs_out = (l == 1) ? hsB : hsA;
        for (int ch = 0; ch < 4; ++ch) {
            gemm_bias_kernel<<<2048, 256, 0, stream>>>(
                src + (size_t)ch * 16384 * K, wih[l], bih[l], bhh[l], xpj, 16384, 2048, K);
            lstm_chunk_kernel<<<256, 256, 0, stream>>>(
                xpj, whh[l], hs_out, cst,
                hTbase + (size_t)l * 262144, cTbase + (size_t)l * 262144,
                barbase + (size_t)(l * 4 + ch) * 4096, ch * 32);
        }
        src = hs_out;
    }
    outproj_kernel<<<2048, 256, 0, stream>>>(hs_out, Wout, bout, out);
}